// Round 2
// baseline (687.484 us; speedup 1.0000x reference)
//
#include <hip/hip_runtime.h>
#include <cstdint>
#include <cstddef>

// Problem constants
#define T_TOKENS 4096
#define DM 1024
#define DF 4096
#define NE 8
#define TOPK 2
#define BK 32
#define MAX_MT 72   // max sum over experts of ceil(count_e/128); worst case 71
#define MSLOTS 8192 // TOPK * T_TOKENS

typedef short short8 __attribute__((ext_vector_type(8)));
typedef float f32x4 __attribute__((ext_vector_type(4)));

__device__ __forceinline__ unsigned short f2h_bits(float f) {
  _Float16 h = (_Float16)f;   // RNE
  union { _Float16 h; unsigned short u; } v; v.h = h; return v.u;
}

typedef __attribute__((address_space(3))) void lds_void_t;
typedef __attribute__((address_space(1))) void gvoid_t;
__device__ __forceinline__ void gl_lds16(const void* g, void* l) {
  __builtin_amdgcn_global_load_lds((gvoid_t*)g, (lds_void_t*)l, 16, 0, 0);
}

// ------------- gate: fp32 logits, top-2, softmax, histogram; also emit Xh fp16 -------------
__global__ void gate_kernel(const float* __restrict__ x, const float* __restrict__ Wg,
                            int* __restrict__ sel, float* __restrict__ wts,
                            int* __restrict__ counts, unsigned short* __restrict__ Xh) {
  int wave = threadIdx.x >> 6, lane = threadIdx.x & 63;
  int t = blockIdx.x * 4 + wave;
  const float* xr = x + (size_t)t * DM;
  unsigned short* xh = Xh + (size_t)t * DM;
  float acc[NE];
#pragma unroll
  for (int e = 0; e < NE; e++) acc[e] = 0.f;
#pragma unroll
  for (int j = 0; j < 4; j++) {
    int d4 = (lane + 64 * j) * 4;
    float4 v = *(const float4*)(xr + d4);
    ushort4 o;
    o.x = f2h_bits(v.x); o.y = f2h_bits(v.y); o.z = f2h_bits(v.z); o.w = f2h_bits(v.w);
    *(ushort4*)(xh + d4) = o;
    const float* wr = Wg + (size_t)d4 * NE;
#pragma unroll
    for (int e = 0; e < NE; e++) acc[e] += v.x * wr[e];
#pragma unroll
    for (int e = 0; e < NE; e++) acc[e] += v.y * wr[NE + e];
#pragma unroll
    for (int e = 0; e < NE; e++) acc[e] += v.z * wr[2 * NE + e];
#pragma unroll
    for (int e = 0; e < NE; e++) acc[e] += v.w * wr[3 * NE + e];
  }
#pragma unroll
  for (int e = 0; e < NE; e++) {
    float v = acc[e];
#pragma unroll
    for (int off = 32; off > 0; off >>= 1) v += __shfl_down(v, off, 64);
    acc[e] = v;
  }
  if (lane == 0) {
    int b0 = 0;
#pragma unroll
    for (int e = 1; e < NE; e++) if (acc[e] > acc[b0]) b0 = e;   // first-index tie-break
    int b1 = (b0 == 0) ? 1 : 0;
#pragma unroll
    for (int e = 0; e < NE; e++) if (e != b0 && acc[e] > acc[b1]) b1 = e;
    float p = expf(acc[b1] - acc[b0]);
    float w0 = 1.f / (1.f + p);
    sel[t * 2] = b0; sel[t * 2 + 1] = b1;
    wts[t * 2] = w0; wts[t * 2 + 1] = p * w0;
    atomicAdd(&counts[b0], 1);
    atomicAdd(&counts[b1], 1);
  }
}

// ---------------- scan: offsets, gemm tile offsets, cursors ----------------
__global__ void scan_kernel(const int* __restrict__ counts, int* __restrict__ offsets,
                            int* __restrict__ tile_off, int* __restrict__ cursors) {
  if (threadIdx.x == 0) {
    int o = 0, to = 0;
    offsets[0] = 0; tile_off[0] = 0;
    for (int e = 0; e < NE; e++) {
      cursors[e] = o;
      o += counts[e];
      to += (counts[e] + 127) >> 7;
      offsets[e + 1] = o;
      tile_off[e + 1] = to;
    }
  }
}

// ---------------- scatter: token -> compacted slot lists + inverse map ----------------
__global__ void scatter_kernel(const int* __restrict__ sel, const float* __restrict__ wts,
                               int* __restrict__ cursors, int* __restrict__ rows,
                               float* __restrict__ rw, int* __restrict__ inv) {
  int t = blockIdx.x * 256 + threadIdx.x;
  if (t >= T_TOKENS) return;
#pragma unroll
  for (int k = 0; k < TOPK; k++) {
    int e = sel[t * 2 + k];
    int slot = atomicAdd(&cursors[e], 1);
    rows[slot] = t;
    rw[slot] = wts[t * 2 + k];
    inv[t * 2 + k] = slot;
  }
}

// ------- fp32 -> fp16 transpose, both weights in ONE launch -------
__global__ void transpose_convert(const float* __restrict__ W1, unsigned short* __restrict__ W1t,
                                  const float* __restrict__ W2, unsigned short* __restrict__ W2t) {
  __shared__ float tile[64 * 65];
  int z = blockIdx.y;
  int R, C;
  const float* inE;
  unsigned short* outE;
  int tidx = blockIdx.x;   // 1024 tiles per expert-matrix
  int bx, by;
  if (z < 8) {
    R = DM; C = DF;
    inE = W1 + (size_t)z * DM * DF;
    outE = W1t + (size_t)z * DM * DF;
    bx = tidx % (DF / 64); by = tidx / (DF / 64);
  } else {
    R = DF; C = DM;
    inE = W2 + (size_t)(z - 8) * DM * DF;
    outE = W2t + (size_t)(z - 8) * DM * DF;
    bx = tidx % (DM / 64); by = tidx / (DM / 64);
  }
  int c0 = bx * 64, r0 = by * 64;
  int tid = threadIdx.x;
  int rr = tid >> 4, c4 = (tid & 15) * 4;
#pragma unroll
  for (int it = 0; it < 4; it++) {
    int r = rr + 16 * it;
    float4 v = *(const float4*)(inE + (size_t)(r0 + r) * C + c0 + c4);
    tile[r * 65 + c4 + 0] = v.x;
    tile[r * 65 + c4 + 1] = v.y;
    tile[r * 65 + c4 + 2] = v.z;
    tile[r * 65 + c4 + 3] = v.w;
  }
  __syncthreads();
#pragma unroll
  for (int it = 0; it < 2; it++) {
    int idx = tid + 256 * it;           // 512 ushort8 units: c = idx>>3, r8 = (idx&7)*8
    int c = idx >> 3, r8 = (idx & 7) * 8;
    short8 val;
#pragma unroll
    for (int j = 0; j < 8; j++) val[j] = (short)f2h_bits(tile[(r8 + j) * 65 + c]);
    *(short8*)(outE + (size_t)(c0 + c) * R + r0 + r8) = val;
  }
}

// ---------------- grouped GEMM: C = A(MxK) * Bt(NxK)^T ----------------
// Double-buffered T3-minimum prefetch loop (one barrier per K-step; stage(next) overlaps
// compute(cur)). LDS seg-XOR swizzle per rule 21: linear global_load_lds dest +
// inverse-swizzled global SOURCE (seg_l = seg ^ ((row>>1)&3)) + swizzled ds_read.
// NSPLIT: split-K partials into Sout + ks*MSLOTS*N (SECOND only); bias added by ks==0.
template <int K, int N, int NT, int NSPLIT, bool INDIR, bool SECOND>
__global__ __launch_bounds__(256, 4) void moe_gemm(
    const unsigned short* __restrict__ Aall, const unsigned short* __restrict__ Ball,
    unsigned short* __restrict__ Hout, float* __restrict__ Sout,
    const float* __restrict__ bias, const int* __restrict__ counts,
    const int* __restrict__ offsets, const int* __restrict__ tile_off,
    const int* __restrict__ rows, const float* __restrict__ rw) {
  // 2 buffers x (4096 A + 4096 B) shorts = 32 KB; epilogue reuses first 8704 shorts
  __shared__ __align__(16) unsigned short lds[16384];

  int id = blockIdx.x;
  int nt = id % NT;               // consecutive ids -> different XCDs share the A m-tile
  int rest = id / NT;
  int ks = rest % NSPLIT;
  int bx = rest / NSPLIT;
  int e = 0;
#pragma unroll 1
  while (e < NE && bx >= tile_off[e + 1]) e++;
  if (e >= NE) return;
  int lt = bx - tile_off[e];
  int cnt = counts[e];
  int m0 = lt * 128;
  int rowbase = offsets[e];
  int n0 = nt * 128;

  const int KS = K / NSPLIT;      // 1024 (GEMM1) or 2048 (GEMM2 split-K)
  const int kbeg = ks * KS;

  const unsigned short* Be = Ball + ((size_t)e * N + n0) * K + kbeg;

  int tid = threadIdx.x;
  int lane = tid & 63, wave = tid >> 6;
  int wm = wave & 1, wn = wave >> 1;

  // staging: thread tid owns physical (row, seg): row = tid>>2 (and +64), seg = tid&3.
  // source uses logical seg_l = seg ^ ((row>>1)&3) (same for row and row+64).
  int rA0 = tid >> 2, rA1 = (256 + tid) >> 2;
  int segl = (tid & 3) ^ ((rA0 >> 1) & 3);
  int mA0 = m0 + rA0; if (mA0 >= cnt) mA0 = cnt - 1;
  int mA1 = m0 + rA1; if (mA1 >= cnt) mA1 = cnt - 1;
  size_t ia0 = INDIR ? (size_t)rows[rowbase + mA0] : (size_t)(rowbase + mA0);
  size_t ia1 = INDIR ? (size_t)rows[rowbase + mA1] : (size_t)(rowbase + mA1);
  const unsigned short* srcA0 = Aall + ia0 * K + kbeg + segl * 8;
  const unsigned short* srcA1 = Aall + ia1 * K + kbeg + segl * 8;
  const unsigned short* srcB0 = Be + (size_t)rA0 * K + segl * 8;
  const unsigned short* srcB1 = Be + (size_t)rA1 * K + segl * 8;

  // fragment read offsets (swizzled), constant across K-steps
  int quad = lane >> 4, c15 = lane & 15;
  int sp = ((quad ^ ((c15 >> 1) & 3))) * 8;
  int aoff[4], boff[4];
#pragma unroll
  for (int t4 = 0; t4 < 4; t4++) {
    aoff[t4] = (wm * 64 + t4 * 16 + c15) * BK + sp;
    boff[t4] = (wn * 64 + t4 * 16 + c15) * BK + sp;
  }

  f32x4 acc[4][4] = {};

  auto stage = [&](int buf, int kk) {
    unsigned short* base = lds + (buf << 13);
    gl_lds16(srcA0 + kk, base + (size_t)tid * 8);
    gl_lds16(srcA1 + kk, base + (size_t)(256 + tid) * 8);
    gl_lds16(srcB0 + kk, base + 4096 + (size_t)tid * 8);
    gl_lds16(srcB1 + kk, base + 4096 + (size_t)(256 + tid) * 8);
  };
  auto compute = [&](int buf) {
    const unsigned short* bA = lds + (buf << 13);
    const unsigned short* bB = bA + 4096;
    short8 af[4], bfr[4];
#pragma unroll
    for (int t4 = 0; t4 < 4; t4++) {
      af[t4]  = *(const short8*)(bA + aoff[t4]);
      bfr[t4] = *(const short8*)(bB + boff[t4]);
    }
#pragma unroll
    for (int tm = 0; tm < 4; tm++)
#pragma unroll
      for (int tn = 0; tn < 4; tn++)
        acc[tm][tn] = __builtin_amdgcn_mfma_f32_16x16x32_f16(af[tm], bfr[tn], acc[tm][tn], 0, 0, 0);
  };

  stage(0, 0);
  __syncthreads();
  const int NK = KS / BK;   // 32 or 64 -> always even
#pragma unroll 1
  for (int it = 0; it < NK; it += 2) {
    if (it + 1 < NK) stage(1, (it + 1) * BK);
    compute(0);
    __syncthreads();
    if (it + 2 < NK) stage(0, (it + 2) * BK);
    compute(1);
    __syncthreads();
  }

  // epilogue: C/D layout col=lane&15, row=(lane>>4)*4+reg
  if constexpr (!SECOND) {
    // stage 64 rows at a time in LDS (fp16, stride 136), then coalesced short8 stores
#pragma unroll 1
    for (int half = 0; half < 2; half++) {
      __syncthreads();
      if (wm == half) {
#pragma unroll
        for (int tm = 0; tm < 4; tm++) {
#pragma unroll
          for (int tn = 0; tn < 4; tn++) {
            int colL = wn * 64 + tn * 16 + c15;
            float b = bias[e * N + n0 + colL];
#pragma unroll
            for (int r = 0; r < 4; r++) {
              int rl = tm * 16 + quad * 4 + r;   // 0..63
              float v = fmaxf(acc[tm][tn][r] + b, 0.f);
              lds[rl * 136 + colL] = f2h_bits(v);
            }
          }
        }
      }
      __syncthreads();
#pragma unroll
      for (int i = 0; i < 4; i++) {
        int idx = tid + 256 * i;                 // 1024 ushort8 units
        int row = idx >> 4, c8 = (idx & 15) * 8;
        int grow = m0 + half * 64 + row;
        if (grow < cnt) {
          short8 val = *(const short8*)(lds + row * 136 + c8);
          *(short8*)(Hout + (size_t)(rowbase + grow) * N + n0 + c8) = val;
        }
      }
    }
  } else {
    float* So = Sout + (size_t)ks * ((size_t)MSLOTS * N);
#pragma unroll
    for (int tm = 0; tm < 4; tm++) {
#pragma unroll
      for (int tn = 0; tn < 4; tn++) {
        int gcol = n0 + wn * 64 + tn * 16 + c15;
        float b = (ks == 0) ? bias[e * N + gcol] : 0.f;
#pragma unroll
        for (int r = 0; r < 4; r++) {
          int rl = wm * 64 + tm * 16 + quad * 4 + r;
          if (m0 + rl < cnt) {
            int slot = rowbase + m0 + rl;
            So[(size_t)slot * N + gcol] = (acc[tm][tn][r] + b) * rw[slot];
          }
        }
      }
    }
  }
}

// ---------------- combine: out[t] = sum over split-K partials of both picked slots ----------------
__global__ void combine_kernel(const float* __restrict__ S, const int* __restrict__ inv,
                               float* __restrict__ out) {
  int wave = threadIdx.x >> 6, lane = threadIdx.x & 63;
  int t = blockIdx.x * 4 + wave;
  int s0 = inv[t * 2], s1 = inv[t * 2 + 1];
  const size_t HALF4 = (size_t)MSLOTS * DM / 4;   // float4 units between split-K partials
  const float4* a0 = (const float4*)S + (size_t)s0 * (DM / 4);
  const float4* a1 = a0 + HALF4;
  const float4* b0 = (const float4*)S + (size_t)s1 * (DM / 4);
  const float4* b1 = b0 + HALF4;
  float4* o = (float4*)(out + (size_t)t * DM);
#pragma unroll
  for (int j = 0; j < 4; j++) {
    int i = lane + 64 * j;
    float4 va = a0[i], vb = a1[i], vc = b0[i], vd = b1[i];
    float4 vo;
    vo.x = (va.x + vb.x) + (vc.x + vd.x);
    vo.y = (va.y + vb.y) + (vc.y + vd.y);
    vo.z = (va.z + vb.z) + (vc.z + vd.z);
    vo.w = (va.w + vb.w) + (vc.w + vd.w);
    o[i] = vo;
  }
}

extern "C" void kernel_launch(void* const* d_in, const int* in_sizes, int n_in,
                              void* d_out, int out_size, void* d_ws, size_t ws_size,
                              hipStream_t stream) {
  const float* x  = (const float*)d_in[0];
  const float* Wg = (const float*)d_in[1];
  const float* W1 = (const float*)d_in[2];
  const float* b1 = (const float*)d_in[3];
  const float* W2 = (const float*)d_in[4];
  const float* b2 = (const float*)d_in[5];
  float* out = (float*)d_out;

  char* ws = (char*)d_ws;
  int*   counts   = (int*)(ws + 0);
  int*   cursors  = (int*)(ws + 64);
  int*   offsets  = (int*)(ws + 128);
  int*   tile_off = (int*)(ws + 192);
  int*   sel      = (int*)(ws + 256);                  // 32 KB
  float* wts      = (float*)(ws + 33024);              // 32 KB
  int*   rows     = (int*)(ws + 65792);                // 32 KB
  float* rw       = (float*)(ws + 98560);              // 32 KB
  int*   inv      = (int*)(ws + 131328);               // 32 KB
  unsigned short* Xh  = (unsigned short*)(ws + 164096);                    // 8.39 MB
  unsigned short* H   = (unsigned short*)(ws + 8552704);                   // 67.1 MB
  unsigned short* W1t = (unsigned short*)(ws + 75661568);                  // 67.1 MB
  float*          S   = (float*)(ws + 75661568);                           // aliases W1t (dead after GEMM1); S0+S1 = 67.1 MB exactly
  unsigned short* W2t = (unsigned short*)(ws + 142770432);                 // 67.1 MB; end = 209.9 MB

  hipMemsetAsync(ws, 0, 128, stream);   // counts + cursors

  gate_kernel<<<T_TOKENS / 4, 256, 0, stream>>>(x, Wg, sel, wts, counts, Xh);
  scan_kernel<<<1, 64, 0, stream>>>(counts, offsets, tile_off, cursors);
  scatter_kernel<<<T_TOKENS / 256, 256, 0, stream>>>(sel, wts, cursors, rows, rw, inv);
  // W1 (E, D, F) -> W1t (E, F, D);  W2 (E, F, D) -> W2t (E, D, F), single launch
  transpose_convert<<<dim3(1024, 16), 256, 0, stream>>>(W1, W1t, W2, W2t);

  moe_gemm<DM, DF, 32, 1, true, false><<<MAX_MT * 32, 256, 0, stream>>>(
      Xh, W1t, H, nullptr, b1, counts, offsets, tile_off, rows, rw);
  moe_gemm<DF, DM, 8, 2, false, true><<<MAX_MT * 8 * 2, 256, 0, stream>>>(
      H, W2t, nullptr, S, b2, counts, offsets, tile_off, rows, rw);

  combine_kernel<<<T_TOKENS / 4, 256, 0, stream>>>(S, inv, out);
}

// Round 3
// 677.094 us; speedup vs baseline: 1.0153x; 1.0153x over previous
//
#include <hip/hip_runtime.h>
#include <cstdint>
#include <cstddef>

// Problem constants
#define T_TOKENS 4096
#define DM 1024
#define DF 4096
#define NE 8
#define TOPK 2
#define BK 32
#define MAX_MT 72   // max sum over experts of ceil(count_e/128); worst case 71
#define MSLOTS 8192 // TOPK * T_TOKENS

typedef short short8 __attribute__((ext_vector_type(8)));
typedef float f32x4 __attribute__((ext_vector_type(4)));

__device__ __forceinline__ unsigned short f2h_bits(float f) {
  _Float16 h = (_Float16)f;   // RNE
  union { _Float16 h; unsigned short u; } v; v.h = h; return v.u;
}

typedef __attribute__((address_space(3))) void lds_void_t;
typedef __attribute__((address_space(1))) void gvoid_t;
__device__ __forceinline__ void gl_lds16(const void* g, void* l) {
  __builtin_amdgcn_global_load_lds((gvoid_t*)g, (lds_void_t*)l, 16, 0, 0);
}

// ------------- gate: fp32 logits, top-2, softmax, histogram; also emit Xh fp16 -------------
__global__ void gate_kernel(const float* __restrict__ x, const float* __restrict__ Wg,
                            int* __restrict__ sel, float* __restrict__ wts,
                            int* __restrict__ counts, unsigned short* __restrict__ Xh) {
  int wave = threadIdx.x >> 6, lane = threadIdx.x & 63;
  int t = blockIdx.x * 4 + wave;
  const float* xr = x + (size_t)t * DM;
  unsigned short* xh = Xh + (size_t)t * DM;
  float acc[NE];
#pragma unroll
  for (int e = 0; e < NE; e++) acc[e] = 0.f;
#pragma unroll
  for (int j = 0; j < 4; j++) {
    int d4 = (lane + 64 * j) * 4;
    float4 v = *(const float4*)(xr + d4);
    ushort4 o;
    o.x = f2h_bits(v.x); o.y = f2h_bits(v.y); o.z = f2h_bits(v.z); o.w = f2h_bits(v.w);
    *(ushort4*)(xh + d4) = o;
    const float* wr = Wg + (size_t)d4 * NE;
#pragma unroll
    for (int e = 0; e < NE; e++) acc[e] += v.x * wr[e];
#pragma unroll
    for (int e = 0; e < NE; e++) acc[e] += v.y * wr[NE + e];
#pragma unroll
    for (int e = 0; e < NE; e++) acc[e] += v.z * wr[2 * NE + e];
#pragma unroll
    for (int e = 0; e < NE; e++) acc[e] += v.w * wr[3 * NE + e];
  }
#pragma unroll
  for (int e = 0; e < NE; e++) {
    float v = acc[e];
#pragma unroll
    for (int off = 32; off > 0; off >>= 1) v += __shfl_down(v, off, 64);
    acc[e] = v;
  }
  if (lane == 0) {
    int b0 = 0;
#pragma unroll
    for (int e = 1; e < NE; e++) if (acc[e] > acc[b0]) b0 = e;   // first-index tie-break
    int b1 = (b0 == 0) ? 1 : 0;
#pragma unroll
    for (int e = 0; e < NE; e++) if (e != b0 && acc[e] > acc[b1]) b1 = e;
    float p = expf(acc[b1] - acc[b0]);
    float w0 = 1.f / (1.f + p);
    sel[t * 2] = b0; sel[t * 2 + 1] = b1;
    wts[t * 2] = w0; wts[t * 2 + 1] = p * w0;
    atomicAdd(&counts[b0], 1);
    atomicAdd(&counts[b1], 1);
  }
}

// ---------------- scan: offsets, gemm tile offsets, cursors ----------------
__global__ void scan_kernel(const int* __restrict__ counts, int* __restrict__ offsets,
                            int* __restrict__ tile_off, int* __restrict__ cursors) {
  if (threadIdx.x == 0) {
    int o = 0, to = 0;
    offsets[0] = 0; tile_off[0] = 0;
    for (int e = 0; e < NE; e++) {
      cursors[e] = o;
      o += counts[e];
      to += (counts[e] + 127) >> 7;
      offsets[e + 1] = o;
      tile_off[e + 1] = to;
    }
  }
}

// ---------------- scatter: token -> compacted slot lists + inverse map ----------------
__global__ void scatter_kernel(const int* __restrict__ sel, const float* __restrict__ wts,
                               int* __restrict__ cursors, int* __restrict__ rows,
                               float* __restrict__ rw, int* __restrict__ inv) {
  int t = blockIdx.x * 256 + threadIdx.x;
  if (t >= T_TOKENS) return;
#pragma unroll
  for (int k = 0; k < TOPK; k++) {
    int e = sel[t * 2 + k];
    int slot = atomicAdd(&cursors[e], 1);
    rows[slot] = t;
    rw[slot] = wts[t * 2 + k];
    inv[t * 2 + k] = slot;
  }
}

// ------- fp32 -> fp16 transpose, both weights in ONE launch -------
__global__ void transpose_convert(const float* __restrict__ W1, unsigned short* __restrict__ W1t,
                                  const float* __restrict__ W2, unsigned short* __restrict__ W2t) {
  __shared__ float tile[64 * 65];
  int z = blockIdx.y;
  int R, C;
  const float* inE;
  unsigned short* outE;
  int tidx = blockIdx.x;   // 1024 tiles per expert-matrix
  int bx, by;
  if (z < 8) {
    R = DM; C = DF;
    inE = W1 + (size_t)z * DM * DF;
    outE = W1t + (size_t)z * DM * DF;
    bx = tidx % (DF / 64); by = tidx / (DF / 64);
  } else {
    R = DF; C = DM;
    inE = W2 + (size_t)(z - 8) * DM * DF;
    outE = W2t + (size_t)(z - 8) * DM * DF;
    bx = tidx % (DM / 64); by = tidx / (DM / 64);
  }
  int c0 = bx * 64, r0 = by * 64;
  int tid = threadIdx.x;
  int rr = tid >> 4, c4 = (tid & 15) * 4;
#pragma unroll
  for (int it = 0; it < 4; it++) {
    int r = rr + 16 * it;
    float4 v = *(const float4*)(inE + (size_t)(r0 + r) * C + c0 + c4);
    tile[r * 65 + c4 + 0] = v.x;
    tile[r * 65 + c4 + 1] = v.y;
    tile[r * 65 + c4 + 2] = v.z;
    tile[r * 65 + c4 + 3] = v.w;
  }
  __syncthreads();
#pragma unroll
  for (int it = 0; it < 2; it++) {
    int idx = tid + 256 * it;           // 512 ushort8 units: c = idx>>3, r8 = (idx&7)*8
    int c = idx >> 3, r8 = (idx & 7) * 8;
    short8 val;
#pragma unroll
    for (int j = 0; j < 8; j++) val[j] = (short)f2h_bits(tile[(r8 + j) * 65 + c]);
    *(short8*)(outE + (size_t)(c0 + c) * R + r0 + r8) = val;
  }
}

// ---------------- grouped GEMM: C = A(MxK) * Bt(NxK)^T ----------------
// T4 counted-vmcnt pipeline: 2 LDS buffers, 2 stages in flight, s_waitcnt vmcnt(4)
// per step (NEVER 0 in the main loop), raw s_barrier. A load issued at the end of
// step t is waited at step t+2 -> one full K-step of latency hiding.
// LDS seg-XOR swizzle (rule 21): linear gl_lds dest + inverse-swizzled global SOURCE
// (seg_l = seg ^ ((row>>1)&3)) + swizzled ds_read. Bank conflicts measured 0.
// NSPLIT: split-K partials into Sout + ks*MSLOTS*N (SECOND only); bias added by ks==0.
template <int K, int N, int NT, int NSPLIT, bool INDIR, bool SECOND>
__global__ __launch_bounds__(256, 4) void moe_gemm(
    const unsigned short* __restrict__ Aall, const unsigned short* __restrict__ Ball,
    unsigned short* __restrict__ Hout, float* __restrict__ Sout,
    const float* __restrict__ bias, const int* __restrict__ counts,
    const int* __restrict__ offsets, const int* __restrict__ tile_off,
    const int* __restrict__ rows, const float* __restrict__ rw) {
  // 2 buffers x (4096 A + 4096 B) shorts = 32 KB; epilogue reuses 64x136 region
  __shared__ __align__(16) unsigned short lds[16384];

  int id = blockIdx.x;
  int nt = id % NT;               // consecutive ids -> different XCDs share the A m-tile
  int rest = id / NT;
  int ks = rest % NSPLIT;
  int bx = rest / NSPLIT;
  int e = 0;
#pragma unroll 1
  while (e < NE && bx >= tile_off[e + 1]) e++;
  if (e >= NE) return;
  int lt = bx - tile_off[e];
  int cnt = counts[e];
  int m0 = lt * 128;
  int rowbase = offsets[e];
  int n0 = nt * 128;

  const int KS = K / NSPLIT;      // 1024 (GEMM1) or 2048 (GEMM2 split-K)
  const int kbeg = ks * KS;

  const unsigned short* Be = Ball + ((size_t)e * N + n0) * K + kbeg;

  int tid = threadIdx.x;
  int lane = tid & 63, wave = tid >> 6;
  int wm = wave & 1, wn = wave >> 1;

  // staging: thread tid owns physical (row, seg): row = tid>>2 (and +64), seg = tid&3.
  // source uses logical seg_l = seg ^ ((row>>1)&3) (same for row and row+64).
  int rA0 = tid >> 2, rA1 = (256 + tid) >> 2;
  int segl = (tid & 3) ^ ((rA0 >> 1) & 3);
  int mA0 = m0 + rA0; if (mA0 >= cnt) mA0 = cnt - 1;
  int mA1 = m0 + rA1; if (mA1 >= cnt) mA1 = cnt - 1;
  size_t ia0 = INDIR ? (size_t)rows[rowbase + mA0] : (size_t)(rowbase + mA0);
  size_t ia1 = INDIR ? (size_t)rows[rowbase + mA1] : (size_t)(rowbase + mA1);
  const unsigned short* srcA0 = Aall + ia0 * K + kbeg + segl * 8;
  const unsigned short* srcA1 = Aall + ia1 * K + kbeg + segl * 8;
  const unsigned short* srcB0 = Be + (size_t)rA0 * K + segl * 8;
  const unsigned short* srcB1 = Be + (size_t)rA1 * K + segl * 8;

  // fragment read offsets (swizzled), constant across K-steps
  int quad = lane >> 4, c15 = lane & 15;
  int sp = ((quad ^ ((c15 >> 1) & 3))) * 8;
  int aoff[4], boff[4];
#pragma unroll
  for (int t4 = 0; t4 < 4; t4++) {
    aoff[t4] = (wm * 64 + t4 * 16 + c15) * BK + sp;
    boff[t4] = (wn * 64 + t4 * 16 + c15) * BK + sp;
  }

  f32x4 acc[4][4] = {};

  auto stage = [&](int buf, int kk) {
    unsigned short* base = lds + (buf << 13);
    gl_lds16(srcA0 + kk, base + (size_t)tid * 8);
    gl_lds16(srcA1 + kk, base + (size_t)(256 + tid) * 8);
    gl_lds16(srcB0 + kk, base + 4096 + (size_t)tid * 8);
    gl_lds16(srcB1 + kk, base + 4096 + (size_t)(256 + tid) * 8);
  };
  auto compute = [&](int buf) {
    const unsigned short* bA = lds + (buf << 13);
    const unsigned short* bB = bA + 4096;
    short8 af[4], bfr[4];
#pragma unroll
    for (int t4 = 0; t4 < 4; t4++) {
      af[t4]  = *(const short8*)(bA + aoff[t4]);
      bfr[t4] = *(const short8*)(bB + boff[t4]);
    }
    __builtin_amdgcn_s_setprio(1);
#pragma unroll
    for (int tm = 0; tm < 4; tm++)
#pragma unroll
      for (int tn = 0; tn < 4; tn++)
        acc[tm][tn] = __builtin_amdgcn_mfma_f32_16x16x32_f16(af[tm], bfr[tn], acc[tm][tn], 0, 0, 0);
    __builtin_amdgcn_s_setprio(0);
  };

  const int NK = KS / BK;   // 32 (GEMM1) or 64 (GEMM2) -> always >= 2
  // prologue: two K-steps in flight (8 outstanding gl_lds per wave)
  stage(0, 0);
  stage(1, BK);
#pragma unroll 1
  for (int it = 0; it < NK - 1; ++it) {
    // wait ONLY the 4 oldest loads (current buffer); next buffer's 4 stay in flight
    asm volatile("s_waitcnt vmcnt(4)" ::: "memory");
    __builtin_amdgcn_s_barrier();            // all waves' current buffer resident
    compute(it & 1);
    asm volatile("s_waitcnt lgkmcnt(0)" ::: "memory");
    __builtin_amdgcn_sched_barrier(0);       // rule 18: pin ds_reads before WAR fence
    __builtin_amdgcn_s_barrier();            // all waves done READING this buffer
    if (it + 2 < NK) stage(it & 1, (it + 2) * BK);  // refill freed buffer, 2 steps ahead
  }
  // peeled last step: only 4 loads outstanding -> must drain fully
  asm volatile("s_waitcnt vmcnt(0)" ::: "memory");
  __builtin_amdgcn_s_barrier();
  compute((NK - 1) & 1);

  // epilogue: C/D layout col=lane&15, row=(lane>>4)*4+reg
  if constexpr (!SECOND) {
    // stage 64 rows at a time in LDS (fp16, stride 136), then coalesced short8 stores
#pragma unroll 1
    for (int half = 0; half < 2; half++) {
      __syncthreads();
      if (wm == half) {
#pragma unroll
        for (int tm = 0; tm < 4; tm++) {
#pragma unroll
          for (int tn = 0; tn < 4; tn++) {
            int colL = wn * 64 + tn * 16 + c15;
            float b = bias[e * N + n0 + colL];
#pragma unroll
            for (int r = 0; r < 4; r++) {
              int rl = tm * 16 + quad * 4 + r;   // 0..63
              float v = fmaxf(acc[tm][tn][r] + b, 0.f);
              lds[rl * 136 + colL] = f2h_bits(v);
            }
          }
        }
      }
      __syncthreads();
#pragma unroll
      for (int i = 0; i < 4; i++) {
        int idx = tid + 256 * i;                 // 1024 ushort8 units
        int row = idx >> 4, c8 = (idx & 15) * 8;
        int grow = m0 + half * 64 + row;
        if (grow < cnt) {
          short8 val = *(const short8*)(lds + row * 136 + c8);
          *(short8*)(Hout + (size_t)(rowbase + grow) * N + n0 + c8) = val;
        }
      }
    }
  } else {
    float* So = Sout + (size_t)ks * ((size_t)MSLOTS * N);
#pragma unroll
    for (int tm = 0; tm < 4; tm++) {
#pragma unroll
      for (int tn = 0; tn < 4; tn++) {
        int gcol = n0 + wn * 64 + tn * 16 + c15;
        float b = (ks == 0) ? bias[e * N + gcol] : 0.f;
#pragma unroll
        for (int r = 0; r < 4; r++) {
          int rl = wm * 64 + tm * 16 + quad * 4 + r;
          if (m0 + rl < cnt) {
            int slot = rowbase + m0 + rl;
            So[(size_t)slot * N + gcol] = (acc[tm][tn][r] + b) * rw[slot];
          }
        }
      }
    }
  }
}

// ---------------- combine: out[t] = sum over split-K partials of both picked slots ----------------
__global__ void combine_kernel(const float* __restrict__ S, const int* __restrict__ inv,
                               float* __restrict__ out) {
  int wave = threadIdx.x >> 6, lane = threadIdx.x & 63;
  int t = blockIdx.x * 4 + wave;
  int s0 = inv[t * 2], s1 = inv[t * 2 + 1];
  const size_t HALF4 = (size_t)MSLOTS * DM / 4;   // float4 units between split-K partials
  const float4* a0 = (const float4*)S + (size_t)s0 * (DM / 4);
  const float4* a1 = a0 + HALF4;
  const float4* b0 = (const float4*)S + (size_t)s1 * (DM / 4);
  const float4* b1 = b0 + HALF4;
  float4* o = (float4*)(out + (size_t)t * DM);
#pragma unroll
  for (int j = 0; j < 4; j++) {
    int i = lane + 64 * j;
    float4 va = a0[i], vb = a1[i], vc = b0[i], vd = b1[i];
    float4 vo;
    vo.x = (va.x + vb.x) + (vc.x + vd.x);
    vo.y = (va.y + vb.y) + (vc.y + vd.y);
    vo.z = (va.z + vb.z) + (vc.z + vd.z);
    vo.w = (va.w + vb.w) + (vc.w + vd.w);
    o[i] = vo;
  }
}

extern "C" void kernel_launch(void* const* d_in, const int* in_sizes, int n_in,
                              void* d_out, int out_size, void* d_ws, size_t ws_size,
                              hipStream_t stream) {
  const float* x  = (const float*)d_in[0];
  const float* Wg = (const float*)d_in[1];
  const float* W1 = (const float*)d_in[2];
  const float* b1 = (const float*)d_in[3];
  const float* W2 = (const float*)d_in[4];
  const float* b2 = (const float*)d_in[5];
  float* out = (float*)d_out;

  char* ws = (char*)d_ws;
  int*   counts   = (int*)(ws + 0);
  int*   cursors  = (int*)(ws + 64);
  int*   offsets  = (int*)(ws + 128);
  int*   tile_off = (int*)(ws + 192);
  int*   sel      = (int*)(ws + 256);                  // 32 KB
  float* wts      = (float*)(ws + 33024);              // 32 KB
  int*   rows     = (int*)(ws + 65792);                // 32 KB
  float* rw       = (float*)(ws + 98560);              // 32 KB
  int*   inv      = (int*)(ws + 131328);               // 32 KB
  unsigned short* Xh  = (unsigned short*)(ws + 164096);                    // 8.39 MB
  unsigned short* H   = (unsigned short*)(ws + 8552704);                   // 67.1 MB
  unsigned short* W1t = (unsigned short*)(ws + 75661568);                  // 67.1 MB
  float*          S   = (float*)(ws + 75661568);                           // aliases W1t (dead after GEMM1); S0+S1 = 67.1 MB exactly
  unsigned short* W2t = (unsigned short*)(ws + 142770432);                 // 67.1 MB; end = 209.9 MB

  hipMemsetAsync(ws, 0, 128, stream);   // counts + cursors

  gate_kernel<<<T_TOKENS / 4, 256, 0, stream>>>(x, Wg, sel, wts, counts, Xh);
  scan_kernel<<<1, 64, 0, stream>>>(counts, offsets, tile_off, cursors);
  scatter_kernel<<<T_TOKENS / 256, 256, 0, stream>>>(sel, wts, cursors, rows, rw, inv);
  // W1 (E, D, F) -> W1t (E, F, D);  W2 (E, F, D) -> W2t (E, D, F), single launch
  transpose_convert<<<dim3(1024, 16), 256, 0, stream>>>(W1, W1t, W2, W2t);

  moe_gemm<DM, DF, 32, 1, true, false><<<MAX_MT * 32, 256, 0, stream>>>(
      Xh, W1t, H, nullptr, b1, counts, offsets, tile_off, rows, rw);
  moe_gemm<DF, DM, 8, 2, false, true><<<MAX_MT * 8 * 2, 256, 0, stream>>>(
      H, W2t, nullptr, S, b2, counts, offsets, tile_off, rows, rw);

  combine_kernel<<<T_TOKENS / 4, 256, 0, stream>>>(S, inv, out);
}